// Round 8
// baseline (502.349 us; speedup 1.0000x reference)
//
#include <hip/hip_runtime.h>
#include <hip/hip_bf16.h>

using bf16 = __hip_bfloat16;
using frag8 = __attribute__((ext_vector_type(8))) short;  // 8 bf16 (4 VGPRs)
using f32x4 = __attribute__((ext_vector_type(4))) float;  // MFMA C/D

__device__ __forceinline__ short f2bf_bits(float f) {
  bf16 h = __float2bfloat16(f);
  short s; __builtin_memcpy(&s, &h, 2); return s;
}
__device__ __forceinline__ float bfbits2f(unsigned short u) {
  unsigned uu = (unsigned)u << 16; float f; __builtin_memcpy(&f, &uu, 4); return f;
}
__device__ __forceinline__ float wred_sum(float v) {
#pragma unroll
  for (int o = 32; o; o >>= 1) v += __shfl_xor(v, o);
  return v;
}

// ================= prep: flag-detect + param canonicalize + wtilde fold +
// cnt zeroing, all in ONE dispatch (each block self-detects the dtype flag).
struct ConvJob { const void* src; void* dst; int n; int mode; int ksh; };
struct ConvJobs { ConvJob j[28]; };
struct WtJob { const void* wraw; const void* adraw; bf16* out; int H; };
struct WtJobs4 { WtJob j[4]; };

__global__ __launch_bounds__(256) void prep_k(
    const unsigned* __restrict__ xdet, int* __restrict__ flag,
    ConvJobs cjobs, int ncv, WtJobs4 wjobs,
    int* __restrict__ cntA, int nA, int* __restrict__ cntB, int nB)
{
  const int b = blockIdx.x, tid = threadIdx.x;
  if (b >= ncv + 4) {                         // cnt zero region (no flag needed)
    int i = (b - (ncv + 4)) * 256 + tid;
    if (i < nA) cntA[i] = 0;
    else if (i < nA + nB) cntB[i - nA] = 0;
    return;
  }
  __shared__ int sh[256];
  int c = 0;
  for (int i = tid; i < 4096; i += 256) {
    unsigned bb = (xdet[i] >> 8) & 0x7F;
    c += (bb >= 0x3B && bb <= 0x41) ? 1 : 0;
  }
  sh[tid] = c; __syncthreads();
  for (int off = 128; off; off >>= 1) { if (tid < off) sh[tid] += sh[tid + off]; __syncthreads(); }
  const int f = (sh[0] < 2048) ? 1 : 0;
  if (b == 0 && tid == 0) flag[0] = f;

  if (b < ncv) {                              // canonicalize job
    ConvJob J = cjobs.j[b];
    const int Kt = 1 << J.ksh;
    for (int i = tid; i < J.n; i += 256) {
      int si = i;
      if (J.mode == 1) { int n = i >> J.ksh, k = i & (Kt - 1); si = k * 128 + n; }
      float v = f ? ((const float*)J.src)[si] : bfbits2f(((const unsigned short*)J.src)[si]);
      if (J.mode == 1) ((bf16*)J.dst)[i] = __float2bfloat16(v);
      else             ((float*)J.dst)[i] = v;
    }
  } else {                                    // wtilde fold from RAW W and ad
    WtJob J = wjobs.j[b - ncv];               // Wt2[h][k] = sum_d W[k][h*D+d]*ad[h*D+d]
    const int H = J.H, D = 128 / H;
    for (int idx = tid; idx < 16 * 128; idx += 256) {
      int h = idx >> 7, k = idx & 127;
      float s = 0.f;
      if (h < H) {
        for (int d = 0; d < D; d++) {
          int n = h * D + d;
          float wv = f ? ((const float*)J.wraw)[k * 128 + n]
                       : bfbits2f(((const unsigned short*)J.wraw)[k * 128 + n]);
          float av = f ? ((const float*)J.adraw)[n]
                       : bfbits2f(((const unsigned short*)J.adraw)[n]);
          s += wv * av;
        }
      }
      J.out[idx] = __float2bfloat16(s);
    }
  }
}

// ================= GEMM body (shared by merged kernels) =====================
struct GemmJob {
  const void* Av; const bf16* WT; const float* bias; const float* avec;
  bf16* outFull; float* outScore; const int* flagp;
  const bf16* WT2; float* outScore2;
  int M, K, H, H2;
};
__device__ __forceinline__ void gemm_body(const GemmJob& J, int blk) {
  __shared__ __align__(16) bf16 Wt[128 * 136];
  __shared__ __align__(16) bf16 Wt2s[16 * 136];
  const int tid = threadIdx.x;
  const int K = J.K;
  const int isf32 = J.flagp ? J.flagp[0] : 0;
  const int stride = K + 8;
  const int ksh2 = (K == 128) ? 4 : 3;
  const int kunits = K >> 3;
  for (int u = tid; u < 128 * kunits; u += 256) {
    int n = u >> ksh2, kb = u & (kunits - 1);
    frag8 v = *(const frag8*)(J.WT + n * K + kb * 8);
    *(frag8*)(Wt + n * stride + kb * 8) = v;
  }
  if (J.WT2) {
    int n = tid >> 4, kb = tid & 15;
    *(frag8*)(Wt2s + n * 136 + kb * 8) = *(const frag8*)(J.WT2 + n * 128 + kb * 8);
  }
  __syncthreads();

  const int lane = tid & 63, wave = tid >> 6;
  const int quad = lane >> 4, c = lane & 15;
  const int mbase = blk * 64 + wave * 16;
  const int arow = mbase + c;
  const bool rowOK = arow < J.M;

  f32x4 acc[8];
#pragma unroll
  for (int t = 0; t < 8; t++) acc[t] = (f32x4){0.f, 0.f, 0.f, 0.f};
  f32x4 acc2 = (f32x4){0.f, 0.f, 0.f, 0.f};

  for (int ks = 0; ks < K; ks += 32) {
    frag8 af;
    const int k0 = ks + quad * 8;
    if (rowOK) {
      if (isf32) {
        const float4* ap = (const float4*)((const float*)J.Av + (size_t)arow * K + k0);
        float4 v0 = ap[0], v1 = ap[1];
        af[0] = f2bf_bits(v0.x); af[1] = f2bf_bits(v0.y);
        af[2] = f2bf_bits(v0.z); af[3] = f2bf_bits(v0.w);
        af[4] = f2bf_bits(v1.x); af[5] = f2bf_bits(v1.y);
        af[6] = f2bf_bits(v1.z); af[7] = f2bf_bits(v1.w);
      } else {
        af = *(const frag8*)((const bf16*)J.Av + (size_t)arow * K + k0);
      }
    } else {
#pragma unroll
      for (int j = 0; j < 8; j++) af[j] = 0;
    }
#pragma unroll
    for (int t = 0; t < 8; t++) {
      frag8 bfv = *(const frag8*)(Wt + (t * 16 + c) * stride + k0);
      acc[t] = __builtin_amdgcn_mfma_f32_16x16x32_bf16(af, bfv, acc[t], 0, 0, 0);
    }
    if (J.WT2) {
      frag8 b2 = *(const frag8*)(Wt2s + c * 136 + k0);
      acc2 = __builtin_amdgcn_mfma_f32_16x16x32_bf16(af, b2, acc2, 0, 0, 0);
    }
  }

  if (J.outFull) {
#pragma unroll
    for (int t = 0; t < 8; t++) {
#pragma unroll
      for (int r = 0; r < 4; r++) {
        int orow = mbase + quad * 4 + r;
        if (orow < J.M) {
          float v = acc[t][r];
          if (J.bias) v += J.bias[t * 16 + c];
          J.outFull[(size_t)orow * 128 + t * 16 + c] = __float2bfloat16(v);
        }
      }
    }
  }
  if (J.outScore) {
    const int H = J.H;
    const int TPH = 8 / H;
    for (int hh = 0; hh < H; hh++) {
#pragma unroll
      for (int r = 0; r < 4; r++) {
        float p = 0.f;
        for (int tt = 0; tt < TPH; tt++) {
          int t = hh * TPH + tt;
          p += acc[t][r] * J.avec[t * 16 + c];
        }
#pragma unroll
        for (int off = 1; off < 16; off <<= 1) p += __shfl_xor(p, off);
        int orow = mbase + quad * 4 + r;
        if (c == 0 && orow < J.M) J.outScore[(size_t)orow * H + hh] = p;
      }
    }
  }
  if (J.outScore2) {
#pragma unroll
    for (int r = 0; r < 4; r++) {
      int orow = mbase + quad * 4 + r;
      if (c < J.H2 && orow < J.M) J.outScore2[(size_t)orow * J.H2 + c] = acc2[r];
    }
  }
}

// ================= hist ∥ proj-GEMM (one dispatch) ==========================
__global__ __launch_bounds__(256) void histgemm_k(
    GemmJob ja, GemmJob jb, int gsplit,
    const int* __restrict__ dAB, const int* __restrict__ dBA, int E, int geh,
    int* __restrict__ cntB, int* __restrict__ cntA)
{
  const int b = blockIdx.x;
  if (b < 2 * geh) {
    if (b < geh) { int i = b * 256 + threadIdx.x; if (i < E) atomicAdd(&cntB[dAB[i]], 1); }
    else { int i = (b - geh) * 256 + threadIdx.x; if (i < E) atomicAdd(&cntA[dBA[i]], 1); }
    return;
  }
  const int gb = b - 2 * geh;
  if (gb < gsplit) gemm_body(ja, gb);
  else             gemm_body(jb, gb - gsplit);
}

// ================= blocksum (raw per-chunk sums) ============================
__device__ __forceinline__ void blocksum_body(const int* cnt, int N, int* bsum, int blk) {
  __shared__ int sh[256];
  const int tid = threadIdx.x;
  const int beg = blk * 1024;
  const int end = (beg + 1024 < N) ? beg + 1024 : N;
  int loc = 0;
  for (int i = beg + tid; i < end; i += 256) loc += cnt[i];
  sh[tid] = loc; __syncthreads();
  for (int off = 128; off; off >>= 1) { if (tid < off) sh[tid] += sh[tid + off]; __syncthreads(); }
  if (tid == 0) bsum[blk] = sh[0];
}
__global__ __launch_bounds__(256) void blocksum2_k(
    const int* __restrict__ cntB, int NB, int* __restrict__ bsumB, int nbB,
    const int* __restrict__ cntA, int NA, int* __restrict__ bsumA)
{
  int b = blockIdx.x;
  if (b < nbB) blocksum_body(cntB, NB, bsumB, b);
  else         blocksum_body(cntA, NA, bsumA, b - nbB);
}

// ================= writerp (self-offset) ∥ layer-0 GEMM =====================
// writerp blocks are small, parallel, coalesced — no straggler vs gemm blocks.
__device__ __forceinline__ void writerp_body(const int* cnt, int N, const int* bsum,
                                             int* rp, int* cur, int blk) {
  __shared__ int sh[256];
  const int tid = threadIdx.x;
  int offacc = 0;
  for (int i = tid; i < blk; i += 256) offacc += bsum[i];
  sh[tid] = offacc; __syncthreads();
  for (int off = 128; off; off >>= 1) { if (tid < off) sh[tid] += sh[tid + off]; __syncthreads(); }
  const int base = sh[0];
  __syncthreads();

  const int idx0 = blk * 1024 + tid * 4;
  int c[4]; int loc = 0;
#pragma unroll
  for (int j = 0; j < 4; j++) {
    int i = idx0 + j;
    c[j] = (i < N) ? cnt[i] : 0;
    loc += c[j];
  }
  sh[tid] = loc; __syncthreads();
  for (int off = 1; off < 256; off <<= 1) {
    int x = sh[tid];
    int o = (tid >= off) ? sh[tid - off] : 0;
    __syncthreads();
    sh[tid] = x + o;
    __syncthreads();
  }
  int run = base + ((tid == 0) ? 0 : sh[tid - 1]);
#pragma unroll
  for (int j = 0; j < 4; j++) {
    int i = idx0 + j;
    if (i < N) { rp[i] = run; cur[i] = run; }
    run += c[j];
  }
  if (idx0 <= N - 1 && N - 1 < idx0 + 4) rp[N] = run;  // total
}
__global__ __launch_bounds__(256) void wrpgemm_k(
    GemmJob ja, GemmJob jb, int gsplit,
    const int* __restrict__ cntB, int NB, const int* __restrict__ bsumB,
    int* __restrict__ rpAB, int* __restrict__ curB, int nbB,
    const int* __restrict__ cntA, int NA, const int* __restrict__ bsumA,
    int* __restrict__ rpBA, int* __restrict__ curA, int nbA)
{
  const int b = blockIdx.x;
  if (b < nbB + nbA) {
    if (b < nbB) writerp_body(cntB, NB, bsumB, rpAB, curB, b);
    else         writerp_body(cntA, NA, bsumA, rpBA, curA, b - nbB);
    return;
  }
  const int gb = b - (nbB + nbA);
  if (gb < gsplit) gemm_body(ja, gb);
  else             gemm_body(jb, gb - gsplit);
}

// plain dual-GEMM dispatch (layer 1)
__global__ __launch_bounds__(256) void gemm2_k(GemmJob ja, GemmJob jb, int split) {
  if (blockIdx.x < split) gemm_body(ja, blockIdx.x);
  else                    gemm_body(jb, blockIdx.x - split);
}

// ================= XCD-partitioned scatter (STANDALONE — no gemm L2 thrash) =
// 8 block-groups (blockIdx%8 ~ XCD); each group owns a disjoint dst range so
// cur[] atomics and sl[] lines stay XCD-local. Correctness does NOT depend on
// the blockIdx->XCD mapping, only locality.
__global__ __launch_bounds__(256) void scatter8_k(
    const int* __restrict__ sAB, const int* __restrict__ dAB,
    const int* __restrict__ sBA, const int* __restrict__ dBA, int E,
    int* __restrict__ curB, int* __restrict__ slAB,
    int* __restrict__ curA, int* __restrict__ slBA, int NB, int NA)
{
  const int g = blockIdx.x & 7;
  const int sidx = blockIdx.x >> 3;
  const int loB = (int)((long long)NB * g >> 3), hiB = (int)((long long)NB * (g + 1) >> 3);
  const int loA = (int)((long long)NA * g >> 3), hiA = (int)((long long)NA * (g + 1) >> 3);
  const int b0 = sidx * 2048;
#pragma unroll
  for (int j = 0; j < 8; j++) {
    int i = b0 + j * 256 + threadIdx.x;
    if (i < 2 * E) {
      bool ab = i < E;
      int k = ab ? i : i - E;
      int d = ab ? dAB[k] : dBA[k];
      int lo = ab ? loB : loA, hi = ab ? hiB : hiA;
      if (d >= lo && d < hi) {
        int sv = ab ? sAB[k] : sBA[k];
        int pos = atomicAdd((ab ? curB : curA) + d, 1);
        (ab ? slAB : slBA)[pos] = sv;
      }
    }
  }
}

// ================= GAT aggregate (quad-edge, 16B/lane, deep unroll) =========
// One wave per node. Phase 1: stage 64 srcs + p=exp(leaky(as+ad)) to LDS.
// Phase 2: quad qe=lane>>4 handles edge e+qe; lane ql=lane&15 covers dims
// [8ql,8ql+8) via one uint4 (8 bf16). unroll 8 => 8 loads (32 edges) in
// flight per wave. Softmax denom is a hot-loop by-product (dacc += p).
struct AggJob {
  const int* rp; const int* srcl; const float* as_; const float* ad_;
  const bf16* hs; const float* bias; const float* gamma; const float* beta;
  const bf16* resid; bf16* outBf; void* outFinal; const int* flagp;
  int nodeBase, N;
};

template<int H, bool FINAL>
__global__ __launch_bounds__(256) void agg_k(AggJob JA, AggJob JB, int split) {
  const bool first = blockIdx.x < split;
  const AggJob J = first ? JA : JB;
  const int blk = first ? blockIdx.x : blockIdx.x - split;

  __shared__ int   s_src[4][64];
  __shared__ float s_p[4][64 * H];
  const int tid = threadIdx.x;
  const int wave = tid >> 6, lane = tid & 63;
  const int n = blk * 4 + wave;
  if (n >= J.N) return;                        // no block barriers below

  const int beg = J.rp[n], end = J.rp[n + 1];
  const int qe = lane >> 4;                    // edge offset within quad-group
  const int ql = lane & 15;                    // dim group: dims 8*ql..8*ql+7
  const int myh = (H == 4) ? (ql >> 2) : 0;

  float4 adv;
  if (H == 4) adv = *(const float4*)(J.ad_ + (size_t)n * 4);
  else        adv.x = J.ad_[n];

  float a0 = 0.f, a1 = 0.f, a2 = 0.f, a3 = 0.f;
  float a4 = 0.f, a5 = 0.f, a6 = 0.f, a7 = 0.f;
  float dacc = 0.f;
  const int* srcp = J.srcl;
  const float* asp = J.as_;
  const bf16* hsp = J.hs;

  for (int base = beg; base < end; base += 64) {
    const int cn = (end - base < 64) ? end - base : 64;
    if (lane < cn) {
      int s = srcp[base + lane];
      s_src[wave][lane] = s;
      if (H == 4) {
        float4 a = *(const float4*)(asp + (size_t)s * 4);
        float4 o; float v;
        v = a.x + adv.x; v = v > 0.f ? v : 0.2f * v; o.x = __expf(v);
        v = a.y + adv.y; v = v > 0.f ? v : 0.2f * v; o.y = __expf(v);
        v = a.z + adv.z; v = v > 0.f ? v : 0.2f * v; o.z = __expf(v);
        v = a.w + adv.w; v = v > 0.f ? v : 0.2f * v; o.w = __expf(v);
        *(float4*)&s_p[wave][lane * 4] = o;
      } else {
        float v = asp[s] + adv.x;
        v = v > 0.f ? v : 0.2f * v;
        s_p[wave][lane] = __expf(v);
      }
    }
    __builtin_amdgcn_wave_barrier();
#pragma unroll 8
    for (int e = 0; e < cn; e += 4) {
      const int eidx = e + qe;
      const bool val = eidx < cn;
      const int ei = val ? eidx : cn - 1;      // clamp (avoid garbage index)
      const int s = s_src[wave][ei];
      const float p = val ? s_p[wave][ei * H + myh] : 0.f;
      const uint4 u = *(const uint4*)(hsp + (size_t)s * 128 + ql * 8);
      dacc += p;
      a0 += p * bfbits2f((unsigned short)(u.x & 0xFFFF));
      a1 += p * bfbits2f((unsigned short)(u.x >> 16));
      a2 += p * bfbits2f((unsigned short)(u.y & 0xFFFF));
      a3 += p * bfbits2f((unsigned short)(u.y >> 16));
      a4 += p * bfbits2f((unsigned short)(u.z & 0xFFFF));
      a5 += p * bfbits2f((unsigned short)(u.z >> 16));
      a6 += p * bfbits2f((unsigned short)(u.w & 0xFFFF));
      a7 += p * bfbits2f((unsigned short)(u.w >> 16));
    }
    __builtin_amdgcn_wave_barrier();
  }

  // combine the 4 quad edge-partitions (also completes the softmax denom)
#pragma unroll
  for (int o = 16; o <= 32; o <<= 1) {
    a0 += __shfl_xor(a0, o); a1 += __shfl_xor(a1, o);
    a2 += __shfl_xor(a2, o); a3 += __shfl_xor(a3, o);
    a4 += __shfl_xor(a4, o); a5 += __shfl_xor(a5, o);
    a6 += __shfl_xor(a6, o); a7 += __shfl_xor(a7, o);
    dacc += __shfl_xor(dacc, o);
  }
  const float inv = 1.f / (dacc + 1e-16f);

  // epilogue: 8 dims/lane (values duplicated across quads -> LN scale 1/512)
  const float4 bi0 = *(const float4*)(J.bias + ql * 8);
  const float4 bi1 = *(const float4*)(J.bias + ql * 8 + 4);
  float y0 = a0 * inv + bi0.x, y1 = a1 * inv + bi0.y;
  float y2 = a2 * inv + bi0.z, y3 = a3 * inv + bi0.w;
  float y4 = a4 * inv + bi1.x, y5 = a5 * inv + bi1.y;
  float y6 = a6 * inv + bi1.z, y7 = a7 * inv + bi1.w;
  float tsum = wred_sum(y0 + y1 + y2 + y3 + y4 + y5 + y6 + y7);
  float tsq  = wred_sum(y0*y0 + y1*y1 + y2*y2 + y3*y3 + y4*y4 + y5*y5 + y6*y6 + y7*y7);
  float mu = tsum * 0.001953125f;              // 1/512
  float var = tsq * 0.001953125f - mu * mu;
  float rs = rsqrtf(var + 1e-5f);
  const float4 ga0 = *(const float4*)(J.gamma + ql * 8);
  const float4 ga1 = *(const float4*)(J.gamma + ql * 8 + 4);
  const float4 be0 = *(const float4*)(J.beta + ql * 8);
  const float4 be1 = *(const float4*)(J.beta + ql * 8 + 4);
  float z0 = (y0 - mu) * rs * ga0.x + be0.x;
  float z1 = (y1 - mu) * rs * ga0.y + be0.y;
  float z2 = (y2 - mu) * rs * ga0.z + be0.z;
  float z3 = (y3 - mu) * rs * ga0.w + be0.w;
  float z4 = (y4 - mu) * rs * ga1.x + be1.x;
  float z5 = (y5 - mu) * rs * ga1.y + be1.y;
  float z6 = (y6 - mu) * rs * ga1.z + be1.z;
  float z7 = (y7 - mu) * rs * ga1.w + be1.w;
  const uint4 ru = *(const uint4*)(J.resid + (size_t)n * 128 + ql * 8);
  z0 = fmaxf(z0, 0.f) + bfbits2f((unsigned short)(ru.x & 0xFFFF));
  z1 = fmaxf(z1, 0.f) + bfbits2f((unsigned short)(ru.x >> 16));
  z2 = fmaxf(z2, 0.f) + bfbits2f((unsigned short)(ru.y & 0xFFFF));
  z3 = fmaxf(z3, 0.f) + bfbits2f((unsigned short)(ru.y >> 16));
  z4 = fmaxf(z4, 0.f) + bfbits2f((unsigned short)(ru.z & 0xFFFF));
  z5 = fmaxf(z5, 0.f) + bfbits2f((unsigned short)(ru.z >> 16));
  z6 = fmaxf(z6, 0.f) + bfbits2f((unsigned short)(ru.w & 0xFFFF));
  z7 = fmaxf(z7, 0.f) + bfbits2f((unsigned short)(ru.w >> 16));

  if (qe == 0) {
    if constexpr (FINAL) {
      if (J.flagp[0]) {
        float* op = (float*)J.outFinal + (size_t)(J.nodeBase + n) * 128 + ql * 8;
        *(float4*)op = make_float4(z0, z1, z2, z3);
        *(float4*)(op + 4) = make_float4(z4, z5, z6, z7);
      } else {
        uint4 pk;
        pk.x = (unsigned)(unsigned short)f2bf_bits(z0) | ((unsigned)(unsigned short)f2bf_bits(z1) << 16);
        pk.y = (unsigned)(unsigned short)f2bf_bits(z2) | ((unsigned)(unsigned short)f2bf_bits(z3) << 16);
        pk.z = (unsigned)(unsigned short)f2bf_bits(z4) | ((unsigned)(unsigned short)f2bf_bits(z5) << 16);
        pk.w = (unsigned)(unsigned short)f2bf_bits(z6) | ((unsigned)(unsigned short)f2bf_bits(z7) << 16);
        *(uint4*)((bf16*)J.outFinal + (size_t)(J.nodeBase + n) * 128 + ql * 8) = pk;
      }
    } else {
      uint4 pk;
      pk.x = (unsigned)(unsigned short)f2bf_bits(z0) | ((unsigned)(unsigned short)f2bf_bits(z1) << 16);
      pk.y = (unsigned)(unsigned short)f2bf_bits(z2) | ((unsigned)(unsigned short)f2bf_bits(z3) << 16);
      pk.z = (unsigned)(unsigned short)f2bf_bits(z4) | ((unsigned)(unsigned short)f2bf_bits(z5) << 16);
      pk.w = (unsigned)(unsigned short)f2bf_bits(z6) | ((unsigned)(unsigned short)f2bf_bits(z7) << 16);
      *(uint4*)(J.outBf + (size_t)n * 128 + ql * 8) = pk;
    }
  }
}

extern "C" void kernel_launch(void* const* d_in, const int* in_sizes, int n_in,
                              void* d_out, int out_size, void* d_ws, size_t ws_size,
                              hipStream_t stream)
{
  const int NA = in_sizes[0] / 128;
  const int NB = in_sizes[1] / 64;
  const int E  = in_sizes[30] / 2;
  const int* eiAB = (const int*)d_in[30];
  const int* eiBA = (const int*)d_in[31];
  const int* srcAB = eiAB;  const int* dstAB = eiAB + E;
  const int* srcBA = eiBA;  const int* dstBA = eiBA + E;

  char* w = (char*)d_ws;
  size_t used = 0;
  auto alloc = [&](size_t bytes) {
    char* p = w + used;
    used += (bytes + 255) & ~size_t(255);
    return (void*)p;
  };
  int*  flag  = (int*)alloc(256);
  bf16* WcA   = (bf16*)alloc(16384 * 2);
  bf16* WcB   = (bf16*)alloc(8192 * 2);
  bf16* Wc0ab = (bf16*)alloc(16384 * 2);
  bf16* Wc0ba = (bf16*)alloc(16384 * 2);
  bf16* Wc1ab = (bf16*)alloc(16384 * 2);
  bf16* Wc1ba = (bf16*)alloc(16384 * 2);
  bf16* Wt0ab = (bf16*)alloc(16 * 128 * 2);    // folded W*ad tiles
  bf16* Wt0ba = (bf16*)alloc(16 * 128 * 2);
  bf16* Wt1ab = (bf16*)alloc(16 * 128 * 2);
  bf16* Wt1ba = (bf16*)alloc(16 * 128 * 2);
  float* vec  = (float*)alloc(22 * 128 * 4);
  bf16* hA    = (bf16*)alloc((size_t)NA * 128 * 2);
  bf16* hB    = (bf16*)alloc((size_t)NB * 128 * 2);
  bf16* hsAB  = (bf16*)alloc((size_t)NA * 128 * 2);
  bf16* hsBA  = (bf16*)alloc((size_t)NB * 128 * 2);
  float* asAB = (float*)alloc((size_t)NA * 4 * 4);
  float* adAB = (float*)alloc((size_t)NB * 4 * 4);
  float* asBA = (float*)alloc((size_t)NB * 4 * 4);
  float* adBA = (float*)alloc((size_t)NA * 4 * 4);
  int* rpAB = (int*)alloc((size_t)(NB + 1) * 4);
  int* slAB = (int*)alloc((size_t)E * 4);
  int* rpBA = (int*)alloc((size_t)(NA + 1) * 4);
  int* slBA = (int*)alloc((size_t)E * 4);
  int* cntA = (int*)alloc((size_t)NA * 4);
  int* curA = (int*)alloc((size_t)NA * 4);
  int* cntB = (int*)alloc((size_t)NB * 4);
  int* curB = (int*)alloc((size_t)NB * 4);
  int* bsumA = (int*)alloc(256 * 4);
  int* bsumB = (int*)alloc(256 * 4);
  if (used > ws_size) return;  // diagnostic: absmax would equal max|ref| (~6.84)

  auto V = [&](int i) { return vec + 128 * i; };
  // vec slots: 0 pbA, 1 pbB, 2 as0ab, 3 ad0ab, 4 b0ab, 5 as0ba, 6 ad0ba,
  // 7 b0ba, 8 as1ab, 9 ad1ab, 10 b1ab, 11 as1ba, 12 ad1ba, 13 b1ba,
  // 14 g0A, 15 bn0A, 16 g0B, 17 bn0B, 18 g1A, 19 bn1A, 20 g1B, 21 bn1B

  ConvJobs jobs{};
  int nj = 0;
  auto addT = [&](const void* s, void* d, int K) {
    int ksh = (K == 128) ? 7 : 6;
    jobs.j[nj++] = ConvJob{s, d, 128 * K, 1, ksh};
  };
  auto addV = [&](const void* s, void* d) { jobs.j[nj++] = ConvJob{s, d, 128, 0, 7}; };
  addT(d_in[2], WcA, 128);
  addT(d_in[4], WcB, 64);
  addT(d_in[6], Wc0ab, 128);
  addT(d_in[10], Wc0ba, 128);
  addT(d_in[14], Wc1ab, 128);
  addT(d_in[18], Wc1ba, 128);
  const int vsrc[22] = {3, 5, 7, 8, 9, 11, 12, 13, 15, 16, 17, 19, 20, 21, 22, 23, 24, 25, 26, 27, 28, 29};
  for (int i = 0; i < 22; i++) addV(d_in[vsrc[i]], V(i));

  WtJobs4 wj{};
  wj.j[0] = WtJob{d_in[6],  d_in[8],  Wt0ab, 4};
  wj.j[1] = WtJob{d_in[10], d_in[12], Wt0ba, 4};
  wj.j[2] = WtJob{d_in[14], d_in[16], Wt1ab, 1};
  wj.j[3] = WtJob{d_in[18], d_in[20], Wt1ba, 1};

  const int nz = (NA + NB + 255) / 256;
  // D1: prep (flag, canonicalize, wtilde, cnt zero)
  prep_k<<<nj + 4 + nz, 256, 0, stream>>>((const unsigned*)d_in[0], flag, jobs, nj, wj,
                                          cntA, NA, cntB, NB);

  const int geh = (E + 255) / 256;
  const int gA = (NA + 63) / 64, gB = (NB + 63) / 64;
  const int aA = (NA + 3) / 4, aB = (NB + 3) / 4;
  const int nbB = (NB + 1023) / 1024, nbA = (NA + 1023) / 1024;

  // D2: hist (both dirs) ∥ input-projection GEMMs
  {
    GemmJob ja{d_in[0], WcA, V(0), nullptr, hA, nullptr, flag, nullptr, nullptr, NA, 128, 1, 0};
    GemmJob jb{d_in[1], WcB, V(1), nullptr, hB, nullptr, flag, nullptr, nullptr, NB, 64, 1, 0};
    histgemm_k<<<2 * geh + gA + gB, 256, 0, stream>>>(ja, jb, gA, dstAB, dstBA, E, geh,
                                                      cntB, cntA);
  }
  // D3: blocksum
  blocksum2_k<<<nbB + nbA, 256, 0, stream>>>(cntB, NB, bsumB, nbB, cntA, NA, bsumA);
  // D4: writerp ∥ layer-0 GEMMs
  {
    GemmJob ja{hA, Wc0ab, nullptr, V(2), hsAB, asAB, nullptr, Wt0ba, adBA, NA, 128, 4, 4};
    GemmJob jb{hB, Wc0ba, nullptr, V(5), hsBA, asBA, nullptr, Wt0ab, adAB, NB, 128, 4, 4};
    wrpgemm_k<<<nbB + nbA + gA + gB, 256, 0, stream>>>(ja, jb, gA,
                                                       cntB, NB, bsumB, rpAB, curB, nbB,
                                                       cntA, NA, bsumA, rpBA, curA, nbA);
  }
  // D5: XCD-partitioned scatter — STANDALONE (L2 slices stay resident)
  {
    const int nsl = (2 * E + 2047) / 2048;
    scatter8_k<<<8 * nsl, 256, 0, stream>>>(srcAB, dstAB, srcBA, dstBA, E,
                                            curB, slAB, curA, slBA, NB, NA);
  }
  // D6: layer-0 aggregate (H=4, both dirs)
  {
    AggJob ja{rpAB, slAB, asAB, adAB, hsAB, V(4), V(16), V(17), hB, hB, nullptr, nullptr, 0, NB};
    AggJob jb{rpBA, slBA, asBA, adBA, hsBA, V(7), V(14), V(15), hA, hA, nullptr, nullptr, 0, NA};
    agg_k<4, false><<<aB + aA, 256, 0, stream>>>(ja, jb, aB);
  }
  // D7: layer-1 GEMMs
  {
    GemmJob ja{hA, Wc1ab, nullptr, V(8),  hsAB, asAB, nullptr, Wt1ba, adBA, NA, 128, 1, 1};
    GemmJob jb{hB, Wc1ba, nullptr, V(11), hsBA, asBA, nullptr, Wt1ab, adAB, NB, 128, 1, 1};
    gemm2_k<<<gA + gB, 256, 0, stream>>>(ja, jb, gA);
  }
  // D8: layer-1 aggregate (H=1, both dirs, final output)
  {
    AggJob ja{rpAB, slAB, asAB, adAB, hsAB, V(10), V(20), V(21), hB, nullptr, d_out, flag, NA, NB};
    AggJob jb{rpBA, slBA, asBA, adBA, hsBA, V(13), V(18), V(19), hA, nullptr, d_out, flag, 0, NA};
    agg_k<1, true><<<aB + aA, 256, 0, stream>>>(ja, jb, aB);
  }
}

// Round 9
// 409.051 us; speedup vs baseline: 1.2281x; 1.2281x over previous
//
#include <hip/hip_runtime.h>
#include <hip/hip_bf16.h>

using bf16 = __hip_bfloat16;
using frag8 = __attribute__((ext_vector_type(8))) short;  // 8 bf16 (4 VGPRs)
using f32x4 = __attribute__((ext_vector_type(4))) float;  // MFMA C/D

__device__ __forceinline__ short f2bf_bits(float f) {
  bf16 h = __float2bfloat16(f);
  short s; __builtin_memcpy(&s, &h, 2); return s;
}
__device__ __forceinline__ float bfbits2f(unsigned short u) {
  unsigned uu = (unsigned)u << 16; float f; __builtin_memcpy(&f, &uu, 4); return f;
}
__device__ __forceinline__ float wred_sum(float v) {
#pragma unroll
  for (int o = 32; o; o >>= 1) v += __shfl_xor(v, o);
  return v;
}

// ================= prep: flag-detect + param canonicalize + wtilde fold +
// bucket-hist (dst>>wsh, <=256 buckets) — all in ONE dispatch.
struct ConvJob { const void* src; void* dst; int n; int mode; int ksh; };
struct ConvJobs { ConvJob j[28]; };
struct WtJob { const void* wraw; const void* adraw; bf16* out; int H; };
struct WtJobs4 { WtJob j[4]; };

__global__ __launch_bounds__(256) void prep_k(
    const unsigned* __restrict__ xdet, int* __restrict__ flag,
    ConvJobs cjobs, int ncv, WtJobs4 wjobs,
    const int* __restrict__ dAB, const int* __restrict__ dBA, int E, int nch,
    int* __restrict__ gcntB, int* __restrict__ gcntA, int wshB, int wshA)
{
  const int b = blockIdx.x, tid = threadIdx.x;
  if (b >= ncv + 4) {                          // bucket-hist region (no flag)
    __shared__ int h[256];
    h[tid] = 0; __syncthreads();
    const int cb = b - (ncv + 4);
    const bool ab = cb < nch;
    const int* dp = ab ? dAB : dBA;
    int* gc = ab ? gcntB : gcntA;
    const int wsh = ab ? wshB : wshA;
    const int base = (ab ? cb : cb - nch) * 2048;
#pragma unroll
    for (int j = 0; j < 8; j++) {
      int i = base + j * 256 + tid;
      if (i < E) atomicAdd(&h[dp[i] >> wsh], 1);
    }
    __syncthreads();
    if (h[tid]) atomicAdd(&gc[tid], h[tid]);
    return;
  }
  __shared__ int sh[256];
  int c = 0;
  for (int i = tid; i < 4096; i += 256) {
    unsigned bb = (xdet[i] >> 8) & 0x7F;
    c += (bb >= 0x3B && bb <= 0x41) ? 1 : 0;
  }
  sh[tid] = c; __syncthreads();
  for (int off = 128; off; off >>= 1) { if (tid < off) sh[tid] += sh[tid + off]; __syncthreads(); }
  const int f = (sh[0] < 2048) ? 1 : 0;
  if (b == 0 && tid == 0) flag[0] = f;

  if (b < ncv) {                              // canonicalize job
    ConvJob J = cjobs.j[b];
    const int Kt = 1 << J.ksh;
    for (int i = tid; i < J.n; i += 256) {
      int si = i;
      if (J.mode == 1) { int n = i >> J.ksh, k = i & (Kt - 1); si = k * 128 + n; }
      float v = f ? ((const float*)J.src)[si] : bfbits2f(((const unsigned short*)J.src)[si]);
      if (J.mode == 1) ((bf16*)J.dst)[i] = __float2bfloat16(v);
      else             ((float*)J.dst)[i] = v;
    }
  } else {                                    // wtilde fold from RAW W and ad
    WtJob J = wjobs.j[b - ncv];               // Wt2[h][k] = sum_d W[k][h*D+d]*ad[h*D+d]
    const int H = J.H, D = 128 / H;
    for (int idx = tid; idx < 16 * 128; idx += 256) {
      int h = idx >> 7, k = idx & 127;
      float s = 0.f;
      if (h < H) {
        for (int d = 0; d < D; d++) {
          int n = h * D + d;
          float wv = f ? ((const float*)J.wraw)[k * 128 + n]
                       : bfbits2f(((const unsigned short*)J.wraw)[k * 128 + n]);
          float av = f ? ((const float*)J.adraw)[n]
                       : bfbits2f(((const unsigned short*)J.adraw)[n]);
          s += wv * av;
        }
      }
      J.out[idx] = __float2bfloat16(s);
    }
  }
}

// ================= GEMM body (shared by merged kernels) =====================
struct GemmJob {
  const void* Av; const bf16* WT; const float* bias; const float* avec;
  bf16* outFull; float* outScore; const int* flagp;
  const bf16* WT2; float* outScore2;
  int M, K, H, H2;
};
__device__ __forceinline__ void gemm_body(const GemmJob& J, int blk) {
  __shared__ __align__(16) bf16 Wt[128 * 136];
  __shared__ __align__(16) bf16 Wt2s[16 * 136];
  const int tid = threadIdx.x;
  const int K = J.K;
  const int isf32 = J.flagp ? J.flagp[0] : 0;
  const int stride = K + 8;
  const int ksh2 = (K == 128) ? 4 : 3;
  const int kunits = K >> 3;
  for (int u = tid; u < 128 * kunits; u += 256) {
    int n = u >> ksh2, kb = u & (kunits - 1);
    frag8 v = *(const frag8*)(J.WT + n * K + kb * 8);
    *(frag8*)(Wt + n * stride + kb * 8) = v;
  }
  if (J.WT2) {
    int n = tid >> 4, kb = tid & 15;
    *(frag8*)(Wt2s + n * 136 + kb * 8) = *(const frag8*)(J.WT2 + n * 128 + kb * 8);
  }
  __syncthreads();

  const int lane = tid & 63, wave = tid >> 6;
  const int quad = lane >> 4, c = lane & 15;
  const int mbase = blk * 64 + wave * 16;
  const int arow = mbase + c;
  const bool rowOK = arow < J.M;

  f32x4 acc[8];
#pragma unroll
  for (int t = 0; t < 8; t++) acc[t] = (f32x4){0.f, 0.f, 0.f, 0.f};
  f32x4 acc2 = (f32x4){0.f, 0.f, 0.f, 0.f};

  for (int ks = 0; ks < K; ks += 32) {
    frag8 af;
    const int k0 = ks + quad * 8;
    if (rowOK) {
      if (isf32) {
        const float4* ap = (const float4*)((const float*)J.Av + (size_t)arow * K + k0);
        float4 v0 = ap[0], v1 = ap[1];
        af[0] = f2bf_bits(v0.x); af[1] = f2bf_bits(v0.y);
        af[2] = f2bf_bits(v0.z); af[3] = f2bf_bits(v0.w);
        af[4] = f2bf_bits(v1.x); af[5] = f2bf_bits(v1.y);
        af[6] = f2bf_bits(v1.z); af[7] = f2bf_bits(v1.w);
      } else {
        af = *(const frag8*)((const bf16*)J.Av + (size_t)arow * K + k0);
      }
    } else {
#pragma unroll
      for (int j = 0; j < 8; j++) af[j] = 0;
    }
#pragma unroll
    for (int t = 0; t < 8; t++) {
      frag8 bfv = *(const frag8*)(Wt + (t * 16 + c) * stride + k0);
      acc[t] = __builtin_amdgcn_mfma_f32_16x16x32_bf16(af, bfv, acc[t], 0, 0, 0);
    }
    if (J.WT2) {
      frag8 b2 = *(const frag8*)(Wt2s + c * 136 + k0);
      acc2 = __builtin_amdgcn_mfma_f32_16x16x32_bf16(af, b2, acc2, 0, 0, 0);
    }
  }

  if (J.outFull) {
#pragma unroll
    for (int t = 0; t < 8; t++) {
#pragma unroll
      for (int r = 0; r < 4; r++) {
        int orow = mbase + quad * 4 + r;
        if (orow < J.M) {
          float v = acc[t][r];
          if (J.bias) v += J.bias[t * 16 + c];
          J.outFull[(size_t)orow * 128 + t * 16 + c] = __float2bfloat16(v);
        }
      }
    }
  }
  if (J.outScore) {
    const int H = J.H;
    const int TPH = 8 / H;
    for (int hh = 0; hh < H; hh++) {
#pragma unroll
      for (int r = 0; r < 4; r++) {
        float p = 0.f;
        for (int tt = 0; tt < TPH; tt++) {
          int t = hh * TPH + tt;
          p += acc[t][r] * J.avec[t * 16 + c];
        }
#pragma unroll
        for (int off = 1; off < 16; off <<= 1) p += __shfl_xor(p, off);
        int orow = mbase + quad * 4 + r;
        if (c == 0 && orow < J.M) J.outScore[(size_t)orow * H + hh] = p;
      }
    }
  }
  if (J.outScore2) {
#pragma unroll
    for (int r = 0; r < 4; r++) {
      int orow = mbase + quad * 4 + r;
      if (c < J.H2 && orow < J.M) J.outScore2[(size_t)orow * J.H2 + c] = acc2[r];
    }
  }
}

// ================= bucket-scatter (deterministic reservations) ∥ proj GEMM ==
// Per block: LDS hist of its 2048-edge chunk by dst>>wsh, one atomicAdd per
// (block,bucket) reserves a contiguous range, then packed keys (dst<<16|src)
// are written into bucket runs — write-once streams, no per-item atomics.
__global__ __launch_bounds__(256) void bsctgemm_k(
    GemmJob ja, GemmJob jb, int gsplit, int gtot,
    const int* __restrict__ sAB, const int* __restrict__ dAB,
    const int* __restrict__ sBA, const int* __restrict__ dBA, int E, int nch,
    const int* __restrict__ gcntB, int* __restrict__ resvB,
    unsigned* __restrict__ bkeyAB, int nbB,
    const int* __restrict__ gcntA, int* __restrict__ resvA,
    unsigned* __restrict__ bkeyBA, int nbA, int wshB, int wshA)
{
  int b = blockIdx.x;
  if (b < gtot) {
    if (b < gsplit) gemm_body(ja, b);
    else            gemm_body(jb, b - gsplit);
    return;
  }
  b -= gtot;
  const bool ab = b < nch;
  const int* sp = ab ? sAB : sBA;
  const int* dp = ab ? dAB : dBA;
  const int* gc = ab ? gcntB : gcntA;
  int* rv = ab ? resvB : resvA;
  unsigned* bk = ab ? bkeyAB : bkeyBA;
  const int nbuck = ab ? nbB : nbA;
  const int wsh = ab ? wshB : wshA;
  const int tid = threadIdx.x;
  const int cbase = (ab ? b : b - nch) * 2048;

  __shared__ int hh[256], ro[256], gb[256], tmp[256];
  hh[tid] = 0; __syncthreads();
  int sv[8], dv[8];
#pragma unroll
  for (int j = 0; j < 8; j++) {
    int i = cbase + j * 256 + tid;
    if (i < E) { sv[j] = sp[i]; dv[j] = dp[i]; atomicAdd(&hh[dv[j] >> wsh], 1); }
    else dv[j] = -1;
  }
  __syncthreads();
  int g = (tid < nbuck) ? gc[tid] : 0;
  tmp[tid] = g; __syncthreads();
  for (int off = 1; off < 256; off <<= 1) {
    int x = tmp[tid]; int o = (tid >= off) ? tmp[tid - off] : 0;
    __syncthreads(); tmp[tid] = x + o; __syncthreads();
  }
  gb[tid] = tmp[tid] - g;                     // exclusive bucket base
  int c = hh[tid];
  ro[tid] = c ? atomicAdd(&rv[tid], c) : 0;   // block's reservation in bucket
  __syncthreads();
  hh[tid] = 0; __syncthreads();
#pragma unroll
  for (int j = 0; j < 8; j++) {
    if (dv[j] >= 0) {
      int v = dv[j] >> wsh;
      int r = atomicAdd(&hh[v], 1);
      bk[gb[v] + ro[v] + r] = ((unsigned)dv[j] << 16) | (unsigned)sv[j];
    }
  }
}

// ================= final per-bucket scatter + rp build ∥ layer-0 GEMM =======
// One block per bucket: its run covers exactly one window of (1<<wsh) dsts.
// LDS per-dst hist + scan -> rp AND final positions; LDS atomics only; sl
// writes land in one ~10KB contiguous region (no write amplification).
__global__ __launch_bounds__(256) void fsctgemm_k(
    GemmJob ja, GemmJob jb, int gsplit, int gtot,
    const unsigned* __restrict__ bkeyAB, const int* __restrict__ gcntB,
    int* __restrict__ rpAB, int* __restrict__ slAB, int NB, int nbB, int wshB,
    const unsigned* __restrict__ bkeyBA, const int* __restrict__ gcntA,
    int* __restrict__ rpBA, int* __restrict__ slBA, int NA, int nbA, int wshA,
    int E)
{
  int b = blockIdx.x;
  if (b < gtot) {
    if (b < gsplit) gemm_body(ja, b);
    else            gemm_body(jb, b - gsplit);
    return;
  }
  b -= gtot;
  const bool ab = b < nbB;
  const unsigned* bk = ab ? bkeyAB : bkeyBA;
  const int* gc = ab ? gcntB : gcntA;
  int* rp = ab ? rpAB : rpBA;
  int* sl = ab ? slAB : slBA;
  const int N = ab ? NB : NA;
  const int nbuck = ab ? nbB : nbA;
  const int wsh = ab ? wshB : wshA;
  const int bkt = ab ? b : b - nbB;
  const int tid = threadIdx.x;

  __shared__ int tmp[256];
  __shared__ int h[2048];
  int g = (tid < nbuck) ? gc[tid] : 0;
  tmp[tid] = g; __syncthreads();
  for (int off = 1; off < 256; off <<= 1) {
    int x = tmp[tid]; int o = (tid >= off) ? tmp[tid - off] : 0;
    __syncthreads(); tmp[tid] = x + o; __syncthreads();
  }
  const int cnt  = gc[bkt];
  const int base = tmp[bkt] - cnt;            // exclusive base of this bucket
  const int win = 1 << wsh;
  const int d0 = bkt << wsh;
  for (int v = tid; v < win; v += 256) h[v] = 0;
  __syncthreads();
  for (int i = tid; i < cnt; i += 256) {
    int v = (int)(bk[base + i] >> 16) - d0;
    atomicAdd(&h[v], 1);
  }
  __syncthreads();
  const int seg = win >> 8;                   // >=1
  int loc = 0;
  for (int j = 0; j < seg; j++) loc += h[tid * seg + j];
  tmp[tid] = loc; __syncthreads();
  for (int off = 1; off < 256; off <<= 1) {
    int x = tmp[tid]; int o = (tid >= off) ? tmp[tid - off] : 0;
    __syncthreads(); tmp[tid] = x + o; __syncthreads();
  }
  int run = tmp[tid] - loc;
  for (int j = 0; j < seg; j++) { int c = h[tid * seg + j]; h[tid * seg + j] = run; run += c; }
  __syncthreads();
  for (int v = tid; v < win; v += 256) {
    int d = d0 + v;
    if (d < N) rp[d] = base + h[v];
  }
  if (bkt == 0 && tid == 0) rp[N] = E;
  __syncthreads();
  for (int i = tid; i < cnt; i += 256) {
    unsigned k = bk[base + i];
    int v = (int)(k >> 16) - d0;
    int r = atomicAdd(&h[v], 1);
    sl[base + r] = (int)(k & 0xFFFFu);
  }
}

// plain dual-GEMM dispatch (layer 1)
__global__ __launch_bounds__(256) void gemm2_k(GemmJob ja, GemmJob jb, int split) {
  if (blockIdx.x < split) gemm_body(ja, blockIdx.x);
  else                    gemm_body(jb, blockIdx.x - split);
}

// ================= GAT aggregate (quad-edge, 16B/lane, unroll 4) ============
// One wave per node. Phase 1: stage 64 srcs + p=exp(leaky(as+ad)) to LDS.
// Phase 2: quad qe=lane>>4 handles edge e+qe; lane ql=lane&15 covers dims
// [8ql,8ql+8) via one uint4 (8 bf16). Softmax denom is a hot-loop by-product.
// unroll 4 (NOT 8: VGPR 44 dropped occupancy 65->48% and cost +20us — R8).
struct AggJob {
  const int* rp; const int* srcl; const float* as_; const float* ad_;
  const bf16* hs; const float* bias; const float* gamma; const float* beta;
  const bf16* resid; bf16* outBf; void* outFinal; const int* flagp;
  int nodeBase, N;
};

template<int H, bool FINAL>
__global__ __launch_bounds__(256) void agg_k(AggJob JA, AggJob JB, int split) {
  const bool first = blockIdx.x < split;
  const AggJob J = first ? JA : JB;
  const int blk = first ? blockIdx.x : blockIdx.x - split;

  __shared__ int   s_src[4][64];
  __shared__ float s_p[4][64 * H];
  const int tid = threadIdx.x;
  const int wave = tid >> 6, lane = tid & 63;
  const int n = blk * 4 + wave;
  if (n >= J.N) return;                        // no block barriers below

  const int beg = J.rp[n], end = J.rp[n + 1];
  const int qe = lane >> 4;                    // edge offset within quad-group
  const int ql = lane & 15;                    // dim group: dims 8*ql..8*ql+7
  const int myh = (H == 4) ? (ql >> 2) : 0;

  float4 adv;
  if (H == 4) adv = *(const float4*)(J.ad_ + (size_t)n * 4);
  else        adv.x = J.ad_[n];

  float a0 = 0.f, a1 = 0.f, a2 = 0.f, a3 = 0.f;
  float a4 = 0.f, a5 = 0.f, a6 = 0.f, a7 = 0.f;
  float dacc = 0.f;
  const int* srcp = J.srcl;
  const float* asp = J.as_;
  const bf16* hsp = J.hs;

  for (int base = beg; base < end; base += 64) {
    const int cn = (end - base < 64) ? end - base : 64;
    if (lane < cn) {
      int s = srcp[base + lane];
      s_src[wave][lane] = s;
      if (H == 4) {
        float4 a = *(const float4*)(asp + (size_t)s * 4);
        float4 o; float v;
        v = a.x + adv.x; v = v > 0.f ? v : 0.2f * v; o.x = __expf(v);
        v = a.y + adv.y; v = v > 0.f ? v : 0.2f * v; o.y = __expf(v);
        v = a.z + adv.z; v = v > 0.f ? v : 0.2f * v; o.z = __expf(v);
        v = a.w + adv.w; v = v > 0.f ? v : 0.2f * v; o.w = __expf(v);
        *(float4*)&s_p[wave][lane * 4] = o;
      } else {
        float v = asp[s] + adv.x;
        v = v > 0.f ? v : 0.2f * v;
        s_p[wave][lane] = __expf(v);
      }
    }
    __builtin_amdgcn_wave_barrier();
#pragma unroll 4
    for (int e = 0; e < cn; e += 4) {
      const int eidx = e + qe;
      const bool val = eidx < cn;
      const int ei = val ? eidx : cn - 1;      // clamp (avoid garbage index)
      const int s = s_src[wave][ei];
      const float p = val ? s_p[wave][ei * H + myh] : 0.f;
      const uint4 u = *(const uint4*)(hsp + (size_t)s * 128 + ql * 8);
      dacc += p;
      a0 += p * bfbits2f((unsigned short)(u.x & 0xFFFF));
      a1 += p * bfbits2f((unsigned short)(u.x >> 16));
      a2 += p * bfbits2f((unsigned short)(u.y & 0xFFFF));
      a3 += p * bfbits2f((unsigned short)(u.y >> 16));
      a4 += p * bfbits2f((unsigned short)(u.z & 0xFFFF));
      a5 += p * bfbits2f((unsigned short)(u.z >> 16));
      a6 += p * bfbits2f((unsigned short)(u.w & 0xFFFF));
      a7 += p * bfbits2f((unsigned short)(u.w >> 16));
    }
    __builtin_amdgcn_wave_barrier();
  }

  // combine the 4 quad edge-partitions (also completes the softmax denom)
#pragma unroll
  for (int o = 16; o <= 32; o <<= 1) {
    a0 += __shfl_xor(a0, o); a1 += __shfl_xor(a1, o);
    a2 += __shfl_xor(a2, o); a3 += __shfl_xor(a3, o);
    a4 += __shfl_xor(a4, o); a5 += __shfl_xor(a5, o);
    a6 += __shfl_xor(a6, o); a7 += __shfl_xor(a7, o);
    dacc += __shfl_xor(dacc, o);
  }
  const float inv = 1.f / (dacc + 1e-16f);

  // epilogue: 8 dims/lane (values duplicated across quads -> LN scale 1/512)
  const float4 bi0 = *(const float4*)(J.bias + ql * 8);
  const float4 bi1 = *(const float4*)(J.bias + ql * 8 + 4);
  float y0 = a0 * inv + bi0.x, y1 = a1 * inv + bi0.y;
  float y2 = a2 * inv + bi0.z, y3 = a3 * inv + bi0.w;
  float y4 = a4 * inv + bi1.x, y5 = a5 * inv + bi1.y;
  float y6 = a6 * inv + bi1.z, y7 = a7 * inv + bi1.w;
  float tsum = wred_sum(y0 + y1 + y2 + y3 + y4 + y5 + y6 + y7);
  float tsq  = wred_sum(y0*y0 + y1*y1 + y2*y2 + y3*y3 + y4*y4 + y5*y5 + y6*y6 + y7*y7);
  float mu = tsum * 0.001953125f;              // 1/512
  float var = tsq * 0.001953125f - mu * mu;
  float rs = rsqrtf(var + 1e-5f);
  const float4 ga0 = *(const float4*)(J.gamma + ql * 8);
  const float4 ga1 = *(const float4*)(J.gamma + ql * 8 + 4);
  const float4 be0 = *(const float4*)(J.beta + ql * 8);
  const float4 be1 = *(const float4*)(J.beta + ql * 8 + 4);
  float z0 = (y0 - mu) * rs * ga0.x + be0.x;
  float z1 = (y1 - mu) * rs * ga0.y + be0.y;
  float z2 = (y2 - mu) * rs * ga0.z + be0.z;
  float z3 = (y3 - mu) * rs * ga0.w + be0.w;
  float z4 = (y4 - mu) * rs * ga1.x + be1.x;
  float z5 = (y5 - mu) * rs * ga1.y + be1.y;
  float z6 = (y6 - mu) * rs * ga1.z + be1.z;
  float z7 = (y7 - mu) * rs * ga1.w + be1.w;
  const uint4 ru = *(const uint4*)(J.resid + (size_t)n * 128 + ql * 8);
  z0 = fmaxf(z0, 0.f) + bfbits2f((unsigned short)(ru.x & 0xFFFF));
  z1 = fmaxf(z1, 0.f) + bfbits2f((unsigned short)(ru.x >> 16));
  z2 = fmaxf(z2, 0.f) + bfbits2f((unsigned short)(ru.y & 0xFFFF));
  z3 = fmaxf(z3, 0.f) + bfbits2f((unsigned short)(ru.y >> 16));
  z4 = fmaxf(z4, 0.f) + bfbits2f((unsigned short)(ru.z & 0xFFFF));
  z5 = fmaxf(z5, 0.f) + bfbits2f((unsigned short)(ru.z >> 16));
  z6 = fmaxf(z6, 0.f) + bfbits2f((unsigned short)(ru.w & 0xFFFF));
  z7 = fmaxf(z7, 0.f) + bfbits2f((unsigned short)(ru.w >> 16));

  if (qe == 0) {
    if constexpr (FINAL) {
      if (J.flagp[0]) {
        float* op = (float*)J.outFinal + (size_t)(J.nodeBase + n) * 128 + ql * 8;
        *(float4*)op = make_float4(z0, z1, z2, z3);
        *(float4*)(op + 4) = make_float4(z4, z5, z6, z7);
      } else {
        uint4 pk;
        pk.x = (unsigned)(unsigned short)f2bf_bits(z0) | ((unsigned)(unsigned short)f2bf_bits(z1) << 16);
        pk.y = (unsigned)(unsigned short)f2bf_bits(z2) | ((unsigned)(unsigned short)f2bf_bits(z3) << 16);
        pk.z = (unsigned)(unsigned short)f2bf_bits(z4) | ((unsigned)(unsigned short)f2bf_bits(z5) << 16);
        pk.w = (unsigned)(unsigned short)f2bf_bits(z6) | ((unsigned)(unsigned short)f2bf_bits(z7) << 16);
        *(uint4*)((bf16*)J.outFinal + (size_t)(J.nodeBase + n) * 128 + ql * 8) = pk;
      }
    } else {
      uint4 pk;
      pk.x = (unsigned)(unsigned short)f2bf_bits(z0) | ((unsigned)(unsigned short)f2bf_bits(z1) << 16);
      pk.y = (unsigned)(unsigned short)f2bf_bits(z2) | ((unsigned)(unsigned short)f2bf_bits(z3) << 16);
      pk.z = (unsigned)(unsigned short)f2bf_bits(z4) | ((unsigned)(unsigned short)f2bf_bits(z5) << 16);
      pk.w = (unsigned)(unsigned short)f2bf_bits(z6) | ((unsigned)(unsigned short)f2bf_bits(z7) << 16);
      *(uint4*)(J.outBf + (size_t)n * 128 + ql * 8) = pk;
    }
  }
}

extern "C" void kernel_launch(void* const* d_in, const int* in_sizes, int n_in,
                              void* d_out, int out_size, void* d_ws, size_t ws_size,
                              hipStream_t stream)
{
  const int NA = in_sizes[0] / 128;
  const int NB = in_sizes[1] / 64;
  const int E  = in_sizes[30] / 2;
  const int* eiAB = (const int*)d_in[30];
  const int* eiBA = (const int*)d_in[31];
  const int* srcAB = eiAB;  const int* dstAB = eiAB + E;
  const int* srcBA = eiBA;  const int* dstBA = eiBA + E;

  // bucket shift: nbuck = ceil(N / 2^wsh) <= 256
  int wshB = 8; while (((NB - 1) >> wshB) >= 256) wshB++;
  int wshA = 8; while (((NA - 1) >> wshA) >= 256) wshA++;
  const int nbB = ((NB - 1) >> wshB) + 1;
  const int nbA = ((NA - 1) >> wshA) + 1;

  char* w = (char*)d_ws;
  size_t used = 0;
  auto alloc = [&](size_t bytes) {
    char* p = w + used;
    used += (bytes + 255) & ~size_t(255);
    return (void*)p;
  };
  int*  flag  = (int*)alloc(256);
  int*  zarr  = (int*)alloc(4096);             // gcntB,gcntA,resvB,resvA (memset 0)
  int* gcntB = zarr;       int* gcntA = zarr + 256;
  int* resvB = zarr + 512; int* resvA = zarr + 768;
  bf16* WcA   = (bf16*)alloc(16384 * 2);
  bf16* WcB   = (bf16*)alloc(8192 * 2);
  bf16* Wc0ab = (bf16*)alloc(16384 * 2);
  bf16* Wc0ba = (bf16*)alloc(16384 * 2);
  bf16* Wc1ab = (bf16*)alloc(16384 * 2);
  bf16* Wc1ba = (bf16*)alloc(16384 * 2);
  bf16* Wt0ab = (bf16*)alloc(16 * 128 * 2);    // folded W*ad tiles
  bf16* Wt0ba = (bf16*)alloc(16 * 128 * 2);
  bf16* Wt1ab = (bf16*)alloc(16 * 128 * 2);
  bf16* Wt1ba = (bf16*)alloc(16 * 128 * 2);
  float* vec  = (float*)alloc(22 * 128 * 4);
  bf16* hA    = (bf16*)alloc((size_t)NA * 128 * 2);
  bf16* hB    = (bf16*)alloc((size_t)NB * 128 * 2);
  bf16* hsAB  = (bf16*)alloc((size_t)NA * 128 * 2);
  bf16* hsBA  = (bf16*)alloc((size_t)NB * 128 * 2);
  float* asAB = (float*)alloc((size_t)NA * 4 * 4);
  float* adAB = (float*)alloc((size_t)NB * 4 * 4);
  float* asBA = (float*)alloc((size_t)NB * 4 * 4);
  float* adBA = (float*)alloc((size_t)NA * 4 * 4);
  int* rpAB = (int*)alloc((size_t)(NB + 1) * 4);
  int* slAB = (int*)alloc((size_t)E * 4);
  int* rpBA = (int*)alloc((size_t)(NA + 1) * 4);
  int* slBA = (int*)alloc((size_t)E * 4);
  unsigned* bkeyAB = (unsigned*)alloc((size_t)E * 4);
  unsigned* bkeyBA = (unsigned*)alloc((size_t)E * 4);
  if (used > ws_size) return;  // diagnostic: absmax would equal max|ref| (~6.84)

  auto V = [&](int i) { return vec + 128 * i; };
  // vec slots: 0 pbA, 1 pbB, 2 as0ab, 3 ad0ab, 4 b0ab, 5 as0ba, 6 ad0ba,
  // 7 b0ba, 8 as1ab, 9 ad1ab, 10 b1ab, 11 as1ba, 12 ad1ba, 13 b1ba,
  // 14 g0A, 15 bn0A, 16 g0B, 17 bn0B, 18 g1A, 19 bn1A, 20 g1B, 21 bn1B

  ConvJobs jobs{};
  int nj = 0;
  auto addT = [&](const void* s, void* d, int K) {
    int ksh = (K == 128) ? 7 : 6;
    jobs.j[nj++] = ConvJob{s, d, 128 * K, 1, ksh};
  };
  auto addV = [&](const void* s, void* d) { jobs.j[nj++] = ConvJob{s, d, 128, 0, 7}; };
  addT(d_in[2], WcA, 128);
  addT(d_in[4], WcB, 64);
  addT(d_in[6], Wc0ab, 128);
  addT(d_in[10], Wc0ba, 128);
  addT(d_in[14], Wc1ab, 128);
  addT(d_in[18], Wc1ba, 128);
  const int vsrc[22] = {3, 5, 7, 8, 9, 11, 12, 13, 15, 16, 17, 19, 20, 21, 22, 23, 24, 25, 26, 27, 28, 29};
  for (int i = 0; i < 22; i++) addV(d_in[vsrc[i]], V(i));

  WtJobs4 wj{};
  wj.j[0] = WtJob{d_in[6],  d_in[8],  Wt0ab, 4};
  wj.j[1] = WtJob{d_in[10], d_in[12], Wt0ba, 4};
  wj.j[2] = WtJob{d_in[14], d_in[16], Wt1ab, 1};
  wj.j[3] = WtJob{d_in[18], d_in[20], Wt1ba, 1};

  const int nch = (E + 2047) / 2048;
  const int gA = (NA + 63) / 64, gB = (NB + 63) / 64;
  const int aA = (NA + 3) / 4, aB = (NB + 3) / 4;
  const int gtot = gA + gB;

  // D0: zero bucket counters/reservations (stream-ordered, graph-capturable)
  hipMemsetAsync(zarr, 0, 4096, stream);
  // D1: prep (flag, canonicalize, wtilde) + bucket-hist both dirs
  prep_k<<<nj + 4 + 2 * nch, 256, 0, stream>>>((const unsigned*)d_in[0], flag, jobs, nj, wj,
                                               dstAB, dstBA, E, nch, gcntB, gcntA, wshB, wshA);
  // D2: input-projection GEMMs ∥ bucket-scatter both dirs
  {
    GemmJob ja{d_in[0], WcA, V(0), nullptr, hA, nullptr, flag, nullptr, nullptr, NA, 128, 1, 0};
    GemmJob jb{d_in[1], WcB, V(1), nullptr, hB, nullptr, flag, nullptr, nullptr, NB, 64, 1, 0};
    bsctgemm_k<<<gtot + 2 * nch, 256, 0, stream>>>(ja, jb, gA, gtot,
                                                   srcAB, dstAB, srcBA, dstBA, E, nch,
                                                   gcntB, resvB, bkeyAB, nbB,
                                                   gcntA, resvA, bkeyBA, nbA, wshB, wshA);
  }
  // D3: layer-0 GEMMs ∥ final per-bucket scatter + rp build
  {
    GemmJob ja{hA, Wc0ab, nullptr, V(2), hsAB, asAB, nullptr, Wt0ba, adBA, NA, 128, 4, 4};
    GemmJob jb{hB, Wc0ba, nullptr, V(5), hsBA, asBA, nullptr, Wt0ab, adAB, NB, 128, 4, 4};
    fsctgemm_k<<<gtot + nbB + nbA, 256, 0, stream>>>(ja, jb, gA, gtot,
                                                     bkeyAB, gcntB, rpAB, slAB, NB, nbB, wshB,
                                                     bkeyBA, gcntA, rpBA, slBA, NA, nbA, wshA, E);
  }
  // D4: layer-0 aggregate (H=4, both dirs)
  {
    AggJob ja{rpAB, slAB, asAB, adAB, hsAB, V(4), V(16), V(17), hB, hB, nullptr, nullptr, 0, NB};
    AggJob jb{rpBA, slBA, asBA, adBA, hsBA, V(7), V(14), V(15), hA, hA, nullptr, nullptr, 0, NA};
    agg_k<4, false><<<aB + aA, 256, 0, stream>>>(ja, jb, aB);
  }
  // D5: layer-1 GEMMs
  {
    GemmJob ja{hA, Wc1ab, nullptr, V(8),  hsAB, asAB, nullptr, Wt1ba, adBA, NA, 128, 1, 1};
    GemmJob jb{hB, Wc1ba, nullptr, V(11), hsBA, asBA, nullptr, Wt1ab, adAB, NB, 128, 1, 1};
    gemm2_k<<<gtot, 256, 0, stream>>>(ja, jb, gA);
  }
  // D6: layer-1 aggregate (H=1, both dirs, final output)
  {
    AggJob ja{rpAB, slAB, asAB, adAB, hsAB, V(10), V(20), V(21), hB, nullptr, d_out, flag, NA, NB};
    AggJob jb{rpBA, slBA, asBA, adBA, hsBA, V(13), V(18), V(19), hA, nullptr, d_out, flag, 0, NA};
    agg_k<1, true><<<aB + aA, 256, 0, stream>>>(ja, jb, aB);
  }
}

// Round 10
// 401.818 us; speedup vs baseline: 1.2502x; 1.0180x over previous
//
#include <hip/hip_runtime.h>
#include <hip/hip_bf16.h>

using bf16 = __hip_bfloat16;
using frag8 = __attribute__((ext_vector_type(8))) short;  // 8 bf16 (4 VGPRs)
using f32x4 = __attribute__((ext_vector_type(4))) float;  // MFMA C/D

__device__ __forceinline__ short f2bf_bits(float f) {
  bf16 h = __float2bfloat16(f);
  short s; __builtin_memcpy(&s, &h, 2); return s;
}
__device__ __forceinline__ float bfbits2f(unsigned short u) {
  unsigned uu = (unsigned)u << 16; float f; __builtin_memcpy(&f, &uu, 4); return f;
}
__device__ __forceinline__ float wred_sum(float v) {
#pragma unroll
  for (int o = 32; o; o >>= 1) v += __shfl_xor(v, o);
  return v;
}

// ================= prep: flag-detect + param canonicalize + wtilde fold +
// bucket-hist (dst>>wsh, <=256 buckets) — all in ONE dispatch.
struct ConvJob { const void* src; void* dst; int n; int mode; int ksh; };
struct ConvJobs { ConvJob j[28]; };
struct WtJob { const void* wraw; const void* adraw; bf16* out; int H; };
struct WtJobs4 { WtJob j[4]; };

__global__ __launch_bounds__(256) void prep_k(
    const unsigned* __restrict__ xdet, int* __restrict__ flag,
    ConvJobs cjobs, int ncv, WtJobs4 wjobs,
    const int* __restrict__ dAB, const int* __restrict__ dBA, int E, int nch,
    int* __restrict__ gcntB, int* __restrict__ gcntA, int wshB, int wshA)
{
  const int b = blockIdx.x, tid = threadIdx.x;
  if (b >= ncv + 4) {                          // bucket-hist region (no flag)
    __shared__ int h[256];
    h[tid] = 0; __syncthreads();
    const int cb = b - (ncv + 4);
    const bool ab = cb < nch;
    const int* dp = ab ? dAB : dBA;
    int* gc = ab ? gcntB : gcntA;
    const int wsh = ab ? wshB : wshA;
    const int base = (ab ? cb : cb - nch) * 2048;
#pragma unroll
    for (int j = 0; j < 8; j++) {
      int i = base + j * 256 + tid;
      if (i < E) atomicAdd(&h[dp[i] >> wsh], 1);
    }
    __syncthreads();
    if (h[tid]) atomicAdd(&gc[tid], h[tid]);
    return;
  }
  __shared__ int sh[256];
  int c = 0;
  for (int i = tid; i < 4096; i += 256) {
    unsigned bb = (xdet[i] >> 8) & 0x7F;
    c += (bb >= 0x3B && bb <= 0x41) ? 1 : 0;
  }
  sh[tid] = c; __syncthreads();
  for (int off = 128; off; off >>= 1) { if (tid < off) sh[tid] += sh[tid + off]; __syncthreads(); }
  const int f = (sh[0] < 2048) ? 1 : 0;
  if (b == 0 && tid == 0) flag[0] = f;

  if (b < ncv) {                              // canonicalize job
    ConvJob J = cjobs.j[b];
    const int Kt = 1 << J.ksh;
    for (int i = tid; i < J.n; i += 256) {
      int si = i;
      if (J.mode == 1) { int n = i >> J.ksh, k = i & (Kt - 1); si = k * 128 + n; }
      float v = f ? ((const float*)J.src)[si] : bfbits2f(((const unsigned short*)J.src)[si]);
      if (J.mode == 1) ((bf16*)J.dst)[i] = __float2bfloat16(v);
      else             ((float*)J.dst)[i] = v;
    }
  } else {                                    // wtilde fold from RAW W and ad
    WtJob J = wjobs.j[b - ncv];               // Wt2[h][k] = sum_d W[k][h*D+d]*ad[h*D+d]
    const int H = J.H, D = 128 / H;
    for (int idx = tid; idx < 16 * 128; idx += 256) {
      int h = idx >> 7, k = idx & 127;
      float s = 0.f;
      if (h < H) {
        for (int d = 0; d < D; d++) {
          int n = h * D + d;
          float wv = f ? ((const float*)J.wraw)[k * 128 + n]
                       : bfbits2f(((const unsigned short*)J.wraw)[k * 128 + n]);
          float av = f ? ((const float*)J.adraw)[n]
                       : bfbits2f(((const unsigned short*)J.adraw)[n]);
          s += wv * av;
        }
      }
      J.out[idx] = __float2bfloat16(s);
    }
  }
}

// ================= GEMM body (shared by merged kernels) =====================
struct GemmJob {
  const void* Av; const bf16* WT; const float* bias; const float* avec;
  bf16* outFull; float* outScore; const int* flagp;
  const bf16* WT2; float* outScore2;
  int M, K, H, H2;
};
__device__ __forceinline__ void gemm_body(const GemmJob& J, int blk) {
  __shared__ __align__(16) bf16 Wt[128 * 136];
  __shared__ __align__(16) bf16 Wt2s[16 * 136];
  const int tid = threadIdx.x;
  const int K = J.K;
  const int isf32 = J.flagp ? J.flagp[0] : 0;
  const int stride = K + 8;
  const int ksh2 = (K == 128) ? 4 : 3;
  const int kunits = K >> 3;
  for (int u = tid; u < 128 * kunits; u += 256) {
    int n = u >> ksh2, kb = u & (kunits - 1);
    frag8 v = *(const frag8*)(J.WT + n * K + kb * 8);
    *(frag8*)(Wt + n * stride + kb * 8) = v;
  }
  if (J.WT2) {
    int n = tid >> 4, kb = tid & 15;
    *(frag8*)(Wt2s + n * 136 + kb * 8) = *(const frag8*)(J.WT2 + n * 128 + kb * 8);
  }
  __syncthreads();

  const int lane = tid & 63, wave = tid >> 6;
  const int quad = lane >> 4, c = lane & 15;
  const int mbase = blk * 64 + wave * 16;
  const int arow = mbase + c;
  const bool rowOK = arow < J.M;

  f32x4 acc[8];
#pragma unroll
  for (int t = 0; t < 8; t++) acc[t] = (f32x4){0.f, 0.f, 0.f, 0.f};
  f32x4 acc2 = (f32x4){0.f, 0.f, 0.f, 0.f};

  for (int ks = 0; ks < K; ks += 32) {
    frag8 af;
    const int k0 = ks + quad * 8;
    if (rowOK) {
      if (isf32) {
        const float4* ap = (const float4*)((const float*)J.Av + (size_t)arow * K + k0);
        float4 v0 = ap[0], v1 = ap[1];
        af[0] = f2bf_bits(v0.x); af[1] = f2bf_bits(v0.y);
        af[2] = f2bf_bits(v0.z); af[3] = f2bf_bits(v0.w);
        af[4] = f2bf_bits(v1.x); af[5] = f2bf_bits(v1.y);
        af[6] = f2bf_bits(v1.z); af[7] = f2bf_bits(v1.w);
      } else {
        af = *(const frag8*)((const bf16*)J.Av + (size_t)arow * K + k0);
      }
    } else {
#pragma unroll
      for (int j = 0; j < 8; j++) af[j] = 0;
    }
#pragma unroll
    for (int t = 0; t < 8; t++) {
      frag8 bfv = *(const frag8*)(Wt + (t * 16 + c) * stride + k0);
      acc[t] = __builtin_amdgcn_mfma_f32_16x16x32_bf16(af, bfv, acc[t], 0, 0, 0);
    }
    if (J.WT2) {
      frag8 b2 = *(const frag8*)(Wt2s + c * 136 + k0);
      acc2 = __builtin_amdgcn_mfma_f32_16x16x32_bf16(af, b2, acc2, 0, 0, 0);
    }
  }

  if (J.outFull) {
#pragma unroll
    for (int t = 0; t < 8; t++) {
#pragma unroll
      for (int r = 0; r < 4; r++) {
        int orow = mbase + quad * 4 + r;
        if (orow < J.M) {
          float v = acc[t][r];
          if (J.bias) v += J.bias[t * 16 + c];
          J.outFull[(size_t)orow * 128 + t * 16 + c] = __float2bfloat16(v);
        }
      }
    }
  }
  if (J.outScore) {
    const int H = J.H;
    const int TPH = 8 / H;
    for (int hh = 0; hh < H; hh++) {
#pragma unroll
      for (int r = 0; r < 4; r++) {
        float p = 0.f;
        for (int tt = 0; tt < TPH; tt++) {
          int t = hh * TPH + tt;
          p += acc[t][r] * J.avec[t * 16 + c];
        }
#pragma unroll
        for (int off = 1; off < 16; off <<= 1) p += __shfl_xor(p, off);
        int orow = mbase + quad * 4 + r;
        if (c == 0 && orow < J.M) J.outScore[(size_t)orow * H + hh] = p;
      }
    }
  }
  if (J.outScore2) {
#pragma unroll
    for (int r = 0; r < 4; r++) {
      int orow = mbase + quad * 4 + r;
      if (c < J.H2 && orow < J.M) J.outScore2[(size_t)orow * J.H2 + c] = acc2[r];
    }
  }
}

// ================= bucket-scatter (deterministic reservations) ∥ proj GEMM ==
__global__ __launch_bounds__(256) void bsctgemm_k(
    GemmJob ja, GemmJob jb, int gsplit, int gtot,
    const int* __restrict__ sAB, const int* __restrict__ dAB,
    const int* __restrict__ sBA, const int* __restrict__ dBA, int E, int nch,
    const int* __restrict__ gcntB, int* __restrict__ resvB,
    unsigned* __restrict__ bkeyAB, int nbB,
    const int* __restrict__ gcntA, int* __restrict__ resvA,
    unsigned* __restrict__ bkeyBA, int nbA, int wshB, int wshA)
{
  int b = blockIdx.x;
  if (b < gtot) {
    if (b < gsplit) gemm_body(ja, b);
    else            gemm_body(jb, b - gsplit);
    return;
  }
  b -= gtot;
  const bool ab = b < nch;
  const int* sp = ab ? sAB : sBA;
  const int* dp = ab ? dAB : dBA;
  const int* gc = ab ? gcntB : gcntA;
  int* rv = ab ? resvB : resvA;
  unsigned* bk = ab ? bkeyAB : bkeyBA;
  const int nbuck = ab ? nbB : nbA;
  const int wsh = ab ? wshB : wshA;
  const int tid = threadIdx.x;
  const int cbase = (ab ? b : b - nch) * 2048;

  __shared__ int hh[256], ro[256], gb[256], tmp[256];
  hh[tid] = 0; __syncthreads();
  int sv[8], dv[8];
#pragma unroll
  for (int j = 0; j < 8; j++) {
    int i = cbase + j * 256 + tid;
    if (i < E) { sv[j] = sp[i]; dv[j] = dp[i]; atomicAdd(&hh[dv[j] >> wsh], 1); }
    else dv[j] = -1;
  }
  __syncthreads();
  int g = (tid < nbuck) ? gc[tid] : 0;
  tmp[tid] = g; __syncthreads();
  for (int off = 1; off < 256; off <<= 1) {
    int x = tmp[tid]; int o = (tid >= off) ? tmp[tid - off] : 0;
    __syncthreads(); tmp[tid] = x + o; __syncthreads();
  }
  gb[tid] = tmp[tid] - g;                     // exclusive bucket base
  int c = hh[tid];
  ro[tid] = c ? atomicAdd(&rv[tid], c) : 0;   // block's reservation in bucket
  __syncthreads();
  hh[tid] = 0; __syncthreads();
#pragma unroll
  for (int j = 0; j < 8; j++) {
    if (dv[j] >= 0) {
      int v = dv[j] >> wsh;
      int r = atomicAdd(&hh[v], 1);
      bk[gb[v] + ro[v] + r] = ((unsigned)dv[j] << 16) | (unsigned)sv[j];
    }
  }
}

// ================= final per-bucket scatter + rp build ∥ layer-0 GEMM =======
__global__ __launch_bounds__(256) void fsctgemm_k(
    GemmJob ja, GemmJob jb, int gsplit, int gtot,
    const unsigned* __restrict__ bkeyAB, const int* __restrict__ gcntB,
    int* __restrict__ rpAB, int* __restrict__ slAB, int NB, int nbB, int wshB,
    const unsigned* __restrict__ bkeyBA, const int* __restrict__ gcntA,
    int* __restrict__ rpBA, int* __restrict__ slBA, int NA, int nbA, int wshA,
    int E)
{
  int b = blockIdx.x;
  if (b < gtot) {
    if (b < gsplit) gemm_body(ja, b);
    else            gemm_body(jb, b - gsplit);
    return;
  }
  b -= gtot;
  const bool ab = b < nbB;
  const unsigned* bk = ab ? bkeyAB : bkeyBA;
  const int* gc = ab ? gcntB : gcntA;
  int* rp = ab ? rpAB : rpBA;
  int* sl = ab ? slAB : slBA;
  const int N = ab ? NB : NA;
  const int nbuck = ab ? nbB : nbA;
  const int wsh = ab ? wshB : wshA;
  const int bkt = ab ? b : b - nbB;
  const int tid = threadIdx.x;

  __shared__ int tmp[256];
  __shared__ int h[2048];
  int g = (tid < nbuck) ? gc[tid] : 0;
  tmp[tid] = g; __syncthreads();
  for (int off = 1; off < 256; off <<= 1) {
    int x = tmp[tid]; int o = (tid >= off) ? tmp[tid - off] : 0;
    __syncthreads(); tmp[tid] = x + o; __syncthreads();
  }
  const int cnt  = gc[bkt];
  const int base = tmp[bkt] - cnt;            // exclusive base of this bucket
  const int win = 1 << wsh;
  const int d0 = bkt << wsh;
  for (int v = tid; v < win; v += 256) h[v] = 0;
  __syncthreads();
  for (int i = tid; i < cnt; i += 256) {
    int v = (int)(bk[base + i] >> 16) - d0;
    atomicAdd(&h[v], 1);
  }
  __syncthreads();
  const int seg = win >> 8;                   // >=1
  int loc = 0;
  for (int j = 0; j < seg; j++) loc += h[tid * seg + j];
  tmp[tid] = loc; __syncthreads();
  for (int off = 1; off < 256; off <<= 1) {
    int x = tmp[tid]; int o = (tid >= off) ? tmp[tid - off] : 0;
    __syncthreads(); tmp[tid] = x + o; __syncthreads();
  }
  int run = tmp[tid] - loc;
  for (int j = 0; j < seg; j++) { int c = h[tid * seg + j]; h[tid * seg + j] = run; run += c; }
  __syncthreads();
  for (int v = tid; v < win; v += 256) {
    int d = d0 + v;
    if (d < N) rp[d] = base + h[v];
  }
  if (bkt == 0 && tid == 0) rp[N] = E;
  __syncthreads();
  for (int i = tid; i < cnt; i += 256) {
    unsigned k = bk[base + i];
    int v = (int)(k >> 16) - d0;
    int r = atomicAdd(&h[v], 1);
    sl[base + r] = (int)(k & 0xFFFFu);
  }
}

// plain dual-GEMM dispatch (layer 1)
__global__ __launch_bounds__(256) void gemm2_k(GemmJob ja, GemmJob jb, int split) {
  if (blockIdx.x < split) gemm_body(ja, blockIdx.x);
  else                    gemm_body(jb, blockIdx.x - split);
}

// ================= GAT aggregate (quad-edge, 16B/lane, unroll 4) ============
// One wave per node. DIRECTION->XCD SPLIT: g=blockIdx&7 (empirical XCD
// round-robin); g<4 -> direction JA (XCDs 0-3), g>=4 -> JB (XCDs 4-7).
// Halves the per-XCD L2 gather working set (25.6MB -> 12.8MB per table).
// Correctness does NOT depend on the block->XCD mapping, only locality.
// Phase 1: stage 64 srcs + p=exp(leaky(as+ad)) to LDS. Phase 2: quad
// qe=lane>>4 handles edge e+qe; lane ql=lane&15 covers dims [8ql,8ql+8) via
// one uint4. Softmax denom is a hot-loop by-product. unroll 4 (NOT 8 — R8).
struct AggJob {
  const int* rp; const int* srcl; const float* as_; const float* ad_;
  const bf16* hs; const float* bias; const float* gamma; const float* beta;
  const bf16* resid; bf16* outBf; void* outFinal; const int* flagp;
  int nodeBase, N;
};

template<int H, bool FINAL>
__global__ __launch_bounds__(256) void agg_k(AggJob JA, AggJob JB, int nk) {
  const int g = blockIdx.x & 7;
  const bool first = g < 4;
  const AggJob J = first ? JA : JB;
  const int blk = (blockIdx.x >> 3) * 4 + (g & 3);

  __shared__ int   s_src[4][64];
  __shared__ float s_p[4][64 * H];
  const int tid = threadIdx.x;
  const int wave = tid >> 6, lane = tid & 63;
  const int n = blk * 4 + wave;
  if (n >= J.N) return;                        // no block barriers below

  const int beg = J.rp[n], end = J.rp[n + 1];
  const int qe = lane >> 4;                    // edge offset within quad-group
  const int ql = lane & 15;                    // dim group: dims 8*ql..8*ql+7
  const int myh = (H == 4) ? (ql >> 2) : 0;

  float4 adv;
  if (H == 4) adv = *(const float4*)(J.ad_ + (size_t)n * 4);
  else        adv.x = J.ad_[n];

  float a0 = 0.f, a1 = 0.f, a2 = 0.f, a3 = 0.f;
  float a4 = 0.f, a5 = 0.f, a6 = 0.f, a7 = 0.f;
  float dacc = 0.f;
  const int* srcp = J.srcl;
  const float* asp = J.as_;
  const bf16* hsp = J.hs;

  for (int base = beg; base < end; base += 64) {
    const int cn = (end - base < 64) ? end - base : 64;
    if (lane < cn) {
      int s = srcp[base + lane];
      s_src[wave][lane] = s;
      if (H == 4) {
        float4 a = *(const float4*)(asp + (size_t)s * 4);
        float4 o; float v;
        v = a.x + adv.x; v = v > 0.f ? v : 0.2f * v; o.x = __expf(v);
        v = a.y + adv.y; v = v > 0.f ? v : 0.2f * v; o.y = __expf(v);
        v = a.z + adv.z; v = v > 0.f ? v : 0.2f * v; o.z = __expf(v);
        v = a.w + adv.w; v = v > 0.f ? v : 0.2f * v; o.w = __expf(v);
        *(float4*)&s_p[wave][lane * 4] = o;
      } else {
        float v = asp[s] + adv.x;
        v = v > 0.f ? v : 0.2f * v;
        s_p[wave][lane] = __expf(v);
      }
    }
    __builtin_amdgcn_wave_barrier();
#pragma unroll 4
    for (int e = 0; e < cn; e += 4) {
      const int eidx = e + qe;
      const bool val = eidx < cn;
      const int ei = val ? eidx : cn - 1;      // clamp (avoid garbage index)
      const int s = s_src[wave][ei];
      const float p = val ? s_p[wave][ei * H + myh] : 0.f;
      const uint4 u = *(const uint4*)(hsp + (size_t)s * 128 + ql * 8);
      dacc += p;
      a0 += p * bfbits2f((unsigned short)(u.x & 0xFFFF));
      a1 += p * bfbits2f((unsigned short)(u.x >> 16));
      a2 += p * bfbits2f((unsigned short)(u.y & 0xFFFF));
      a3 += p * bfbits2f((unsigned short)(u.y >> 16));
      a4 += p * bfbits2f((unsigned short)(u.z & 0xFFFF));
      a5 += p * bfbits2f((unsigned short)(u.z >> 16));
      a6 += p * bfbits2f((unsigned short)(u.w & 0xFFFF));
      a7 += p * bfbits2f((unsigned short)(u.w >> 16));
    }
    __builtin_amdgcn_wave_barrier();
  }

  // combine the 4 quad edge-partitions (also completes the softmax denom)
#pragma unroll
  for (int o = 16; o <= 32; o <<= 1) {
    a0 += __shfl_xor(a0, o); a1 += __shfl_xor(a1, o);
    a2 += __shfl_xor(a2, o); a3 += __shfl_xor(a3, o);
    a4 += __shfl_xor(a4, o); a5 += __shfl_xor(a5, o);
    a6 += __shfl_xor(a6, o); a7 += __shfl_xor(a7, o);
    dacc += __shfl_xor(dacc, o);
  }
  const float inv = 1.f / (dacc + 1e-16f);

  // epilogue: 8 dims/lane (values duplicated across quads -> LN scale 1/512)
  const float4 bi0 = *(const float4*)(J.bias + ql * 8);
  const float4 bi1 = *(const float4*)(J.bias + ql * 8 + 4);
  float y0 = a0 * inv + bi0.x, y1 = a1 * inv + bi0.y;
  float y2 = a2 * inv + bi0.z, y3 = a3 * inv + bi0.w;
  float y4 = a4 * inv + bi1.x, y5 = a5 * inv + bi1.y;
  float y6 = a6 * inv + bi1.z, y7 = a7 * inv + bi1.w;
  float tsum = wred_sum(y0 + y1 + y2 + y3 + y4 + y5 + y6 + y7);
  float tsq  = wred_sum(y0*y0 + y1*y1 + y2*y2 + y3*y3 + y4*y4 + y5*y5 + y6*y6 + y7*y7);
  float mu = tsum * 0.001953125f;              // 1/512
  float var = tsq * 0.001953125f - mu * mu;
  float rs = rsqrtf(var + 1e-5f);
  const float4 ga0 = *(const float4*)(J.gamma + ql * 8);
  const float4 ga1 = *(const float4*)(J.gamma + ql * 8 + 4);
  const float4 be0 = *(const float4*)(J.beta + ql * 8);
  const float4 be1 = *(const float4*)(J.beta + ql * 8 + 4);
  float z0 = (y0 - mu) * rs * ga0.x + be0.x;
  float z1 = (y1 - mu) * rs * ga0.y + be0.y;
  float z2 = (y2 - mu) * rs * ga0.z + be0.z;
  float z3 = (y3 - mu) * rs * ga0.w + be0.w;
  float z4 = (y4 - mu) * rs * ga1.x + be1.x;
  float z5 = (y5 - mu) * rs * ga1.y + be1.y;
  float z6 = (y6 - mu) * rs * ga1.z + be1.z;
  float z7 = (y7 - mu) * rs * ga1.w + be1.w;
  const uint4 ru = *(const uint4*)(J.resid + (size_t)n * 128 + ql * 8);
  z0 = fmaxf(z0, 0.f) + bfbits2f((unsigned short)(ru.x & 0xFFFF));
  z1 = fmaxf(z1, 0.f) + bfbits2f((unsigned short)(ru.x >> 16));
  z2 = fmaxf(z2, 0.f) + bfbits2f((unsigned short)(ru.y & 0xFFFF));
  z3 = fmaxf(z3, 0.f) + bfbits2f((unsigned short)(ru.y >> 16));
  z4 = fmaxf(z4, 0.f) + bfbits2f((unsigned short)(ru.z & 0xFFFF));
  z5 = fmaxf(z5, 0.f) + bfbits2f((unsigned short)(ru.z >> 16));
  z6 = fmaxf(z6, 0.f) + bfbits2f((unsigned short)(ru.w & 0xFFFF));
  z7 = fmaxf(z7, 0.f) + bfbits2f((unsigned short)(ru.w >> 16));

  if (qe == 0) {
    if constexpr (FINAL) {
      if (J.flagp[0]) {
        float* op = (float*)J.outFinal + (size_t)(J.nodeBase + n) * 128 + ql * 8;
        *(float4*)op = make_float4(z0, z1, z2, z3);
        *(float4*)(op + 4) = make_float4(z4, z5, z6, z7);
      } else {
        uint4 pk;
        pk.x = (unsigned)(unsigned short)f2bf_bits(z0) | ((unsigned)(unsigned short)f2bf_bits(z1) << 16);
        pk.y = (unsigned)(unsigned short)f2bf_bits(z2) | ((unsigned)(unsigned short)f2bf_bits(z3) << 16);
        pk.z = (unsigned)(unsigned short)f2bf_bits(z4) | ((unsigned)(unsigned short)f2bf_bits(z5) << 16);
        pk.w = (unsigned)(unsigned short)f2bf_bits(z6) | ((unsigned)(unsigned short)f2bf_bits(z7) << 16);
        *(uint4*)((bf16*)J.outFinal + (size_t)(J.nodeBase + n) * 128 + ql * 8) = pk;
      }
    } else {
      uint4 pk;
      pk.x = (unsigned)(unsigned short)f2bf_bits(z0) | ((unsigned)(unsigned short)f2bf_bits(z1) << 16);
      pk.y = (unsigned)(unsigned short)f2bf_bits(z2) | ((unsigned)(unsigned short)f2bf_bits(z3) << 16);
      pk.z = (unsigned)(unsigned short)f2bf_bits(z4) | ((unsigned)(unsigned short)f2bf_bits(z5) << 16);
      pk.w = (unsigned)(unsigned short)f2bf_bits(z6) | ((unsigned)(unsigned short)f2bf_bits(z7) << 16);
      *(uint4*)(J.outBf + (size_t)n * 128 + ql * 8) = pk;
    }
  }
}

extern "C" void kernel_launch(void* const* d_in, const int* in_sizes, int n_in,
                              void* d_out, int out_size, void* d_ws, size_t ws_size,
                              hipStream_t stream)
{
  const int NA = in_sizes[0] / 128;
  const int NB = in_sizes[1] / 64;
  const int E  = in_sizes[30] / 2;
  const int* eiAB = (const int*)d_in[30];
  const int* eiBA = (const int*)d_in[31];
  const int* srcAB = eiAB;  const int* dstAB = eiAB + E;
  const int* srcBA = eiBA;  const int* dstBA = eiBA + E;

  // bucket shift: nbuck = ceil(N / 2^wsh) <= 256
  int wshB = 8; while (((NB - 1) >> wshB) >= 256) wshB++;
  int wshA = 8; while (((NA - 1) >> wshA) >= 256) wshA++;
  const int nbB = ((NB - 1) >> wshB) + 1;
  const int nbA = ((NA - 1) >> wshA) + 1;

  char* w = (char*)d_ws;
  size_t used = 0;
  auto alloc = [&](size_t bytes) {
    char* p = w + used;
    used += (bytes + 255) & ~size_t(255);
    return (void*)p;
  };
  int*  flag  = (int*)alloc(256);
  int*  zarr  = (int*)alloc(4096);             // gcntB,gcntA,resvB,resvA (memset 0)
  int* gcntB = zarr;       int* gcntA = zarr + 256;
  int* resvB = zarr + 512; int* resvA = zarr + 768;
  bf16* WcA   = (bf16*)alloc(16384 * 2);
  bf16* WcB   = (bf16*)alloc(8192 * 2);
  bf16* Wc0ab = (bf16*)alloc(16384 * 2);
  bf16* Wc0ba = (bf16*)alloc(16384 * 2);
  bf16* Wc1ab = (bf16*)alloc(16384 * 2);
  bf16* Wc1ba = (bf16*)alloc(16384 * 2);
  bf16* Wt0ab = (bf16*)alloc(16 * 128 * 2);    // folded W*ad tiles
  bf16* Wt0ba = (bf16*)alloc(16 * 128 * 2);
  bf16* Wt1ab = (bf16*)alloc(16 * 128 * 2);
  bf16* Wt1ba = (bf16*)alloc(16 * 128 * 2);
  float* vec  = (float*)alloc(22 * 128 * 4);
  bf16* hA    = (bf16*)alloc((size_t)NA * 128 * 2);
  bf16* hB    = (bf16*)alloc((size_t)NB * 128 * 2);
  bf16* hsAB  = (bf16*)alloc((size_t)NA * 128 * 2);
  bf16* hsBA  = (bf16*)alloc((size_t)NB * 128 * 2);
  float* asAB = (float*)alloc((size_t)NA * 4 * 4);
  float* adAB = (float*)alloc((size_t)NB * 4 * 4);
  float* asBA = (float*)alloc((size_t)NB * 4 * 4);
  float* adBA = (float*)alloc((size_t)NA * 4 * 4);
  int* rpAB = (int*)alloc((size_t)(NB + 1) * 4);
  int* slAB = (int*)alloc((size_t)E * 4);
  int* rpBA = (int*)alloc((size_t)(NA + 1) * 4);
  int* slBA = (int*)alloc((size_t)E * 4);
  unsigned* bkeyAB = (unsigned*)alloc((size_t)E * 4);
  unsigned* bkeyBA = (unsigned*)alloc((size_t)E * 4);
  if (used > ws_size) return;  // diagnostic: absmax would equal max|ref| (~6.84)

  auto V = [&](int i) { return vec + 128 * i; };
  // vec slots: 0 pbA, 1 pbB, 2 as0ab, 3 ad0ab, 4 b0ab, 5 as0ba, 6 ad0ba,
  // 7 b0ba, 8 as1ab, 9 ad1ab, 10 b1ab, 11 as1ba, 12 ad1ba, 13 b1ba,
  // 14 g0A, 15 bn0A, 16 g0B, 17 bn0B, 18 g1A, 19 bn1A, 20 g1B, 21 bn1B

  ConvJobs jobs{};
  int nj = 0;
  auto addT = [&](const void* s, void* d, int K) {
    int ksh = (K == 128) ? 7 : 6;
    jobs.j[nj++] = ConvJob{s, d, 128 * K, 1, ksh};
  };
  auto addV = [&](const void* s, void* d) { jobs.j[nj++] = ConvJob{s, d, 128, 0, 7}; };
  addT(d_in[2], WcA, 128);
  addT(d_in[4], WcB, 64);
  addT(d_in[6], Wc0ab, 128);
  addT(d_in[10], Wc0ba, 128);
  addT(d_in[14], Wc1ab, 128);
  addT(d_in[18], Wc1ba, 128);
  const int vsrc[22] = {3, 5, 7, 8, 9, 11, 12, 13, 15, 16, 17, 19, 20, 21, 22, 23, 24, 25, 26, 27, 28, 29};
  for (int i = 0; i < 22; i++) addV(d_in[vsrc[i]], V(i));

  WtJobs4 wj{};
  wj.j[0] = WtJob{d_in[6],  d_in[8],  Wt0ab, 4};
  wj.j[1] = WtJob{d_in[10], d_in[12], Wt0ba, 4};
  wj.j[2] = WtJob{d_in[14], d_in[16], Wt1ab, 1};
  wj.j[3] = WtJob{d_in[18], d_in[20], Wt1ba, 1};

  const int nch = (E + 2047) / 2048;
  const int gA = (NA + 63) / 64, gB = (NB + 63) / 64;
  const int aA = (NA + 3) / 4, aB = (NB + 3) / 4;
  const int amax = aA > aB ? aA : aB;
  const int nk = (amax + 3) / 4;
  const int gtot = gA + gB;

  // D0: zero bucket counters/reservations (stream-ordered, graph-capturable)
  hipMemsetAsync(zarr, 0, 4096, stream);
  // D1: prep (flag, canonicalize, wtilde) + bucket-hist both dirs
  prep_k<<<nj + 4 + 2 * nch, 256, 0, stream>>>((const unsigned*)d_in[0], flag, jobs, nj, wj,
                                               dstAB, dstBA, E, nch, gcntB, gcntA, wshB, wshA);
  // D2: input-projection GEMMs ∥ bucket-scatter both dirs
  {
    GemmJob ja{d_in[0], WcA, V(0), nullptr, hA, nullptr, flag, nullptr, nullptr, NA, 128, 1, 0};
    GemmJob jb{d_in[1], WcB, V(1), nullptr, hB, nullptr, flag, nullptr, nullptr, NB, 64, 1, 0};
    bsctgemm_k<<<gtot + 2 * nch, 256, 0, stream>>>(ja, jb, gA, gtot,
                                                   srcAB, dstAB, srcBA, dstBA, E, nch,
                                                   gcntB, resvB, bkeyAB, nbB,
                                                   gcntA, resvA, bkeyBA, nbA, wshB, wshA);
  }
  // D3: layer-0 GEMMs ∥ final per-bucket scatter + rp build
  {
    GemmJob ja{hA, Wc0ab, nullptr, V(2), hsAB, asAB, nullptr, Wt0ba, adBA, NA, 128, 4, 4};
    GemmJob jb{hB, Wc0ba, nullptr, V(5), hsBA, asBA, nullptr, Wt0ab, adAB, NB, 128, 4, 4};
    fsctgemm_k<<<gtot + nbB + nbA, 256, 0, stream>>>(ja, jb, gA, gtot,
                                                     bkeyAB, gcntB, rpAB, slAB, NB, nbB, wshB,
                                                     bkeyBA, gcntA, rpBA, slBA, NA, nbA, wshA, E);
  }
  // D4: layer-0 aggregate (H=4, direction->XCD split)
  {
    AggJob ja{rpAB, slAB, asAB, adAB, hsAB, V(4), V(16), V(17), hB, hB, nullptr, nullptr, 0, NB};
    AggJob jb{rpBA, slBA, asBA, adBA, hsBA, V(7), V(14), V(15), hA, hA, nullptr, nullptr, 0, NA};
    agg_k<4, false><<<8 * nk, 256, 0, stream>>>(ja, jb, nk);
  }
  // D5: layer-1 GEMMs
  {
    GemmJob ja{hA, Wc1ab, nullptr, V(8),  hsAB, asAB, nullptr, Wt1ba, adBA, NA, 128, 1, 1};
    GemmJob jb{hB, Wc1ba, nullptr, V(11), hsBA, asBA, nullptr, Wt1ab, adAB, NB, 128, 1, 1};
    gemm2_k<<<gtot, 256, 0, stream>>>(ja, jb, gA);
  }
  // D6: layer-1 aggregate (H=1, direction->XCD split, final output)
  {
    AggJob ja{rpAB, slAB, asAB, adAB, hsAB, V(10), V(20), V(21), hB, nullptr, d_out, flag, NA, NB};
    AggJob jb{rpBA, slBA, asBA, adBA, hsBA, V(13), V(18), V(19), hA, nullptr, d_out, flag, 0, NA};
    agg_k<1, true><<<8 * nk, 256, 0, stream>>>(ja, jb, nk);
  }
}